// Round 1
// baseline (2810.339 us; speedup 1.0000x reference)
//
#include <hip/hip_runtime.h>
#include <math.h>

#define KCL 2048
#define LRELU_NEG 0.01f
#define EPSBN 1e-5f

__device__ __forceinline__ float lrelu(float x) { return x > 0.f ? x : LRELU_NEG * x; }

// monotonic float->uint encoding for atomicMax over mixed-sign floats
__device__ __forceinline__ unsigned encf(float f) {
    unsigned u = __float_as_uint(f);
    return (u & 0x80000000u) ? ~u : (u | 0x80000000u);
}
__device__ __forceinline__ float decf(unsigned u) {
    return __uint_as_float((u & 0x80000000u) ? (u & 0x7fffffffu) : ~u);
}

// BatchNorm1d training-mode apply from accumulated double sums (stats[0:64]=sum, stats[64:128]=sumsq)
__device__ __forceinline__ float bn_apply(float x, const double* __restrict__ stats, int col, int n,
                                          const float* __restrict__ g, const float* __restrict__ b) {
    float mean = (float)(stats[col] / n);
    float ex2  = (float)(stats[64 + col] / n);
    float var  = ex2 - mean * mean;
    float rstd = rsqrtf(fmaxf(var, 0.f) + EPSBN);
    return (x - mean) * rstd * g[col] + b[col];
}

// ---------------- column stats (sum, sumsq) over (n,64), double atomics ----------------
__global__ __launch_bounds__(256) void colstats_kernel(const float* __restrict__ in, int n,
                                                       double* __restrict__ stats) {
    int t = threadIdx.x;
    int col = t & 63, rg = t >> 6;
    double s = 0.0, s2 = 0.0;
    for (long row = (long)blockIdx.x * 4 + rg; row < n; row += (long)gridDim.x * 4) {
        float x = in[row * 64 + col];
        s += x;
        s2 += (double)x * (double)x;
    }
    __shared__ double red[256];
    red[t] = s;
    __syncthreads();
    if (t < 64) atomicAdd(&stats[col], red[t] + red[t + 64] + red[t + 128] + red[t + 192]);
    __syncthreads();
    red[t] = s2;
    __syncthreads();
    if (t < 64) atomicAdd(&stats[64 + col], red[t] + red[t + 64] + red[t + 128] + red[t + 192]);
}

// ---------------- cluster histogram ----------------
__global__ __launch_bounds__(256) void hist_kernel(const int* __restrict__ clus, int* __restrict__ cnt, int n) {
    __shared__ int h[KCL];
    for (int i = threadIdx.x; i < KCL; i += 256) h[i] = 0;
    __syncthreads();
    for (long i = (long)blockIdx.x * 256 + threadIdx.x; i < n; i += (long)gridDim.x * 256)
        atomicAdd(&h[clus[i]], 1);
    __syncthreads();
    for (int i = threadIdx.x; i < KCL; i += 256) {
        int v = h[i];
        if (v) atomicAdd(&cnt[i], v);
    }
}

// ---------------- adaptive weights: softmax(feat @ aW[64,3], axis=1) ----------------
__global__ __launch_bounds__(256) void adp_kernel(const float* __restrict__ feat, const float* __restrict__ aW,
                                                  float* __restrict__ adp, int n) {
    __shared__ float w[192];
    for (int i = threadIdx.x; i < 192; i += 256) w[i] = aW[i];
    __syncthreads();
    for (long row = (long)blockIdx.x * 256 + threadIdx.x; row < n; row += (long)gridDim.x * 256) {
        const float* fr = feat + row * 64;
        float l0 = 0.f, l1 = 0.f, l2 = 0.f;
#pragma unroll 8
        for (int k = 0; k < 64; ++k) {
            float x = fr[k];
            l0 += x * w[k * 3 + 0];
            l1 += x * w[k * 3 + 1];
            l2 += x * w[k * 3 + 2];
        }
        float m = fmaxf(l0, fmaxf(l1, l2));
        float e0 = expf(l0 - m), e1 = expf(l1 - m), e2 = expf(l2 - m);
        float inv = 1.f / (e0 + e1 + e2);
        adp[row * 3 + 0] = e0 * inv;
        adp[row * 3 + 1] = e1 * inv;
        adp[row * 3 + 2] = e2 * inv;
    }
}

// ---------------- (n,64) @ (64,64) with optional pre/post ops ----------------
// PRE: 0 = plain, 2 = subtract per-cluster mean (seg/cnt/clus)
// PMAX: 1 = global max of outputs via atomicMax(enc)
template <int PRE, int PMAX>
__global__ __launch_bounds__(256) void mm64_kernel(const float* __restrict__ in, const float* __restrict__ W,
                                                   float* __restrict__ out, int n,
                                                   const float* __restrict__ seg, const int* __restrict__ cnt,
                                                   const int* __restrict__ clus, unsigned* __restrict__ gmaxp) {
    __shared__ float Wl[64 * 64];
    __shared__ float rs[16 * 64];
    int t = threadIdx.x;
    int col = t & 63, r0 = t >> 6;
    for (int i = t; i < 4096; i += 256) Wl[i] = W[i];
    int rb = blockIdx.x * 16;
    for (int rr = r0; rr < 16; rr += 4) {
        int row = rb + rr;
        float x = 0.f;
        if (row < n) {
            x = in[(size_t)row * 64 + col];
            if (PRE == 2) {
                int c = clus[row];
                float cf = (float)cnt[c];
                if (cf < 1.f) cf = 1.f;
                x -= seg[c * 64 + col] / cf;
            }
        }
        rs[rr * 64 + col] = x;
    }
    __syncthreads();
    float a0 = 0.f, a1 = 0.f, a2 = 0.f, a3 = 0.f;
#pragma unroll 8
    for (int kk = 0; kk < 64; ++kk) {
        float wv = Wl[kk * 64 + col];
        a0 += rs[(r0 + 0) * 64 + kk] * wv;
        a1 += rs[(r0 + 4) * 64 + kk] * wv;
        a2 += rs[(r0 + 8) * 64 + kk] * wv;
        a3 += rs[(r0 + 12) * 64 + kk] * wv;
    }
    if (rb + r0 + 0 < n) out[(size_t)(rb + r0 + 0) * 64 + col] = a0;
    if (rb + r0 + 4 < n) out[(size_t)(rb + r0 + 4) * 64 + col] = a1;
    if (rb + r0 + 8 < n) out[(size_t)(rb + r0 + 8) * 64 + col] = a2;
    if (rb + r0 + 12 < n) out[(size_t)(rb + r0 + 12) * 64 + col] = a3;
    if constexpr (PMAX) {
        float m = -INFINITY;
        if (rb + r0 + 0 < n) m = fmaxf(m, a0);
        if (rb + r0 + 4 < n) m = fmaxf(m, a1);
        if (rb + r0 + 8 < n) m = fmaxf(m, a2);
        if (rb + r0 + 12 < n) m = fmaxf(m, a3);
        __shared__ float red[256];
        red[t] = m;
        __syncthreads();
        for (int s = 128; s > 0; s >>= 1) {
            if (t < s) red[t] = fmaxf(red[t], red[t + s]);
            __syncthreads();
        }
        if (t == 0) atomicMax(gmaxp, encf(red[0]));
    }
}

// ---------------- B = lrelu(bn(A)); seg[c] += B ----------------
__global__ __launch_bounds__(256) void bn_lrelu_segsum_kernel(const float* __restrict__ A,
                                                              const double* __restrict__ stats,
                                                              const float* __restrict__ g, const float* __restrict__ b,
                                                              float* __restrict__ B, float* __restrict__ seg,
                                                              const int* __restrict__ clus, int n) {
    long total = (long)n * 64;
    for (long idx = (long)blockIdx.x * 256 + threadIdx.x; idx < total; idx += (long)gridDim.x * 256) {
        int col = (int)(idx & 63);
        long row = idx >> 6;
        float y = lrelu(bn_apply(A[idx], stats, col, n, g, b));
        B[idx] = y;
        atomicAdd(&seg[(long)clus[row] * 64 + col], y);
    }
}

// ---------------- D = exp(C - gmax) in-place; seg2[c] += D ----------------
__global__ __launch_bounds__(256) void exp_segsum_kernel(float* __restrict__ C, const unsigned* __restrict__ gmaxp,
                                                         float* __restrict__ seg2, const int* __restrict__ clus, int n) {
    float gm = decf(*gmaxp);
    long total = (long)n * 64;
    for (long idx = (long)blockIdx.x * 256 + threadIdx.x; idx < total; idx += (long)gridDim.x * 256) {
        int col = (int)(idx & 63);
        long row = idx >> 6;
        float y = expf(C[idx] - gm);
        C[idx] = y;
        atomicAdd(&seg2[(long)clus[row] * 64 + col], y);
    }
}

// ---------------- pf = lrelu(bn(E)); seg3[c] += pf * D/(seg2[c]+1e-6) ----------------
__global__ __launch_bounds__(256) void bn_lrelu_mul_segsum_kernel(const float* __restrict__ E,
                                                                  const double* __restrict__ stats,
                                                                  const float* __restrict__ g,
                                                                  const float* __restrict__ b,
                                                                  const float* __restrict__ D,
                                                                  const float* __restrict__ seg2,
                                                                  float* __restrict__ seg3,
                                                                  const int* __restrict__ clus, int n) {
    long total = (long)n * 64;
    for (long idx = (long)blockIdx.x * 256 + threadIdx.x; idx < total; idx += (long)gridDim.x * 256) {
        int col = (int)(idx & 63);
        long row = idx >> 6;
        int c = clus[row];
        float pf = lrelu(bn_apply(E[idx], stats, col, n, g, b));
        float pw = D[idx] / (seg2[(long)c * 64 + col] + 1e-6f);
        atomicAdd(&seg3[(long)c * 64 + col], pf * pw);
    }
}

// ---------------- blend += adp[:,lvl] * seg3[c] ----------------
__global__ __launch_bounds__(256) void blend_add_kernel(const float* __restrict__ adp, int lvl,
                                                        const float* __restrict__ seg3, const int* __restrict__ clus,
                                                        float* __restrict__ blend, int n) {
    long total = (long)n * 64;
    for (long idx = (long)blockIdx.x * 256 + threadIdx.x; idx < total; idx += (long)gridDim.x * 256) {
        int col = (int)(idx & 63);
        long row = idx >> 6;
        blend[idx] += adp[row * 3 + lvl] * seg3[(long)clus[row] * 64 + col];
    }
}

// ---------------- t3 = lrelu(bn(P3)) @ Wf[0:64] + blend @ Wf[64:128] ----------------
__global__ __launch_bounds__(256) void fuse_mm_kernel(const float* __restrict__ P3, const double* __restrict__ stats,
                                                      const float* __restrict__ g, const float* __restrict__ b,
                                                      const float* __restrict__ blend, const float* __restrict__ Wf,
                                                      float* __restrict__ out, int n) {
    __shared__ float Wl[128 * 64];
    __shared__ float rs[16 * 128];
    int t = threadIdx.x;
    int col = t & 63, r0 = t >> 6;
    for (int i = t; i < 128 * 64; i += 256) Wl[i] = Wf[i];
    int rb = blockIdx.x * 16;
    for (int rr = r0; rr < 16; rr += 4) {
        int row = rb + rr;
        float xa = 0.f, xb = 0.f;
        if (row < n) {
            xa = lrelu(bn_apply(P3[(size_t)row * 64 + col], stats, col, n, g, b));
            xb = blend[(size_t)row * 64 + col];
        }
        rs[rr * 128 + col] = xa;
        rs[rr * 128 + 64 + col] = xb;
    }
    __syncthreads();
    float a0 = 0.f, a1 = 0.f, a2 = 0.f, a3 = 0.f;
#pragma unroll 8
    for (int kk = 0; kk < 128; ++kk) {
        float wv = Wl[kk * 64 + col];
        a0 += rs[(r0 + 0) * 128 + kk] * wv;
        a1 += rs[(r0 + 4) * 128 + kk] * wv;
        a2 += rs[(r0 + 8) * 128 + kk] * wv;
        a3 += rs[(r0 + 12) * 128 + kk] * wv;
    }
    if (rb + r0 + 0 < n) out[(size_t)(rb + r0 + 0) * 64 + col] = a0;
    if (rb + r0 + 4 < n) out[(size_t)(rb + r0 + 4) * 64 + col] = a1;
    if (rb + r0 + 8 < n) out[(size_t)(rb + r0 + 8) * 64 + col] = a2;
    if (rb + r0 + 12 < n) out[(size_t)(rb + r0 + 12) * 64 + col] = a3;
}

// ---------------- f = lrelu(bn(t3)) + feat ----------------
__global__ __launch_bounds__(256) void bn_lrelu_addfeat_kernel(const float* __restrict__ t3,
                                                               const double* __restrict__ stats,
                                                               const float* __restrict__ g, const float* __restrict__ b,
                                                               const float* __restrict__ feat, float* __restrict__ f,
                                                               int n) {
    long total = (long)n * 64;
    for (long idx = (long)blockIdx.x * 256 + threadIdx.x; idx < total; idx += (long)gridDim.x * 256) {
        int col = (int)(idx & 63);
        f[idx] = lrelu(bn_apply(t3[idx], stats, col, n, g, b)) + feat[idx];
    }
}

// ---------------- submanifold 3x3x3 conv: out = sum_k gather(f,nbr[k]) @ W[k] ----------------
__global__ __launch_bounds__(256) void subm_conv_kernel(const float* __restrict__ fin, const int* __restrict__ nbr,
                                                        const float* __restrict__ Wc, float* __restrict__ vout, int n) {
    __shared__ float Wl[64 * 64];
    __shared__ float gs[64 * 64];
    int t = threadIdx.x;
    int rb = blockIdx.x * 64;
    int tr = t >> 4;  // row tile: rows tr*4 .. tr*4+3
    int tc = t & 15;  // col tile: cols tc*4 .. tc*4+3
    float acc[4][4] = {};
    for (int k = 0; k < 27; ++k) {
        const float* Wk = Wc + (size_t)k * 4096;
        for (int i = t; i < 4096; i += 256) Wl[i] = Wk[i];
        for (int i = t; i < 64 * 64; i += 256) {
            int rr = i >> 6, cc = i & 63;
            int row = rb + rr;
            int gi = (row < n) ? nbr[(size_t)k * n + row] : -1;
            gs[i] = (gi >= 0) ? fin[(size_t)gi * 64 + cc] : 0.f;
        }
        __syncthreads();
#pragma unroll 4
        for (int kk = 0; kk < 64; ++kk) {
            float4 wv = *(const float4*)&Wl[kk * 64 + tc * 4];
#pragma unroll
            for (int j = 0; j < 4; ++j) {
                float av = gs[(tr * 4 + j) * 64 + kk];
                acc[j][0] += av * wv.x;
                acc[j][1] += av * wv.y;
                acc[j][2] += av * wv.z;
                acc[j][3] += av * wv.w;
            }
        }
        __syncthreads();
    }
#pragma unroll
    for (int j = 0; j < 4; ++j) {
        int row = rb + tr * 4 + j;
        if (row < n)
            *(float4*)&vout[(size_t)row * 64 + tc * 4] =
                make_float4(acc[j][0], acc[j][1], acc[j][2], acc[j][3]);
    }
}

// ---------------- u = lrelu(bn(v)) in place ----------------
__global__ __launch_bounds__(256) void bn_lrelu_kernel(float* __restrict__ v, const double* __restrict__ stats,
                                                       const float* __restrict__ g, const float* __restrict__ b, int n) {
    long total = (long)n * 64;
    for (long idx = (long)blockIdx.x * 256 + threadIdx.x; idx < total; idx += (long)gridDim.x * 256) {
        int col = (int)(idx & 63);
        v[idx] = lrelu(bn_apply(v[idx], stats, col, n, g, b));
    }
}

// ---------------- out = lrelu(bn(w) + f) ----------------
__global__ __launch_bounds__(256) void final_kernel(const float* __restrict__ w, const double* __restrict__ stats,
                                                    const float* __restrict__ g, const float* __restrict__ b,
                                                    const float* __restrict__ f, float* __restrict__ out, int n) {
    long total = (long)n * 64;
    for (long idx = (long)blockIdx.x * 256 + threadIdx.x; idx < total; idx += (long)gridDim.x * 256) {
        int col = (int)(idx & 63);
        out[idx] = lrelu(bn_apply(w[idx], stats, col, n, g, b) + f[idx]);
    }
}

extern "C" void kernel_launch(void* const* d_in, const int* in_sizes, int n_in,
                              void* d_out, int out_size, void* d_ws, size_t ws_size,
                              hipStream_t stream) {
    const float* feat = (const float*)d_in[0];
    const float* lw_W = (const float*)d_in[1];
    const float* lw_g = (const float*)d_in[2];
    const float* lw_b = (const float*)d_in[3];
    const float* w_W = (const float*)d_in[4];
    const float* proj_W = (const float*)d_in[5];
    const float* proj_g = (const float*)d_in[6];
    const float* proj_b = (const float*)d_in[7];
    const float* adaptive_W = (const float*)d_in[8];
    const float* fuse_W = (const float*)d_in[9];
    const float* fuse_g = (const float*)d_in[10];
    const float* fuse_b = (const float*)d_in[11];
    const float* conv1_W = (const float*)d_in[12];
    const float* bn1_g = (const float*)d_in[13];
    const float* bn1_b = (const float*)d_in[14];
    const float* conv2_W = (const float*)d_in[15];
    const float* bn2_g = (const float*)d_in[16];
    const float* bn2_b = (const float*)d_in[17];
    const int* clusters = (const int*)d_in[18];
    const int* nbr = (const int*)d_in[19];

    const int n = in_sizes[0] / 64;

    // workspace layout: zeroed region first (one memset per launch)
    char* ws = (char*)d_ws;
    size_t off = 0;
    auto alloc = [&](size_t bytes) -> size_t {
        size_t o = off;
        off = (off + bytes + 255) & ~(size_t)255;
        return o;
    };
    size_t seg_off = alloc((size_t)9 * KCL * 64 * 4);     // 9 segment-sum buffers
    size_t blend_off = alloc((size_t)n * 64 * 4);         // einsum accumulator
    size_t cnt_off = alloc((size_t)3 * KCL * 4);          // cluster counts
    size_t stats_off = alloc((size_t)10 * 128 * 8);       // 10 BN stat slots (double)
    size_t gmax_off = alloc(16);                          // 3 global-max slots
    size_t zbytes = off;                                  // end of zeroed region
    size_t adp_off = alloc((size_t)n * 3 * 4);
    size_t bufA_off = alloc((size_t)n * 64 * 4);
    size_t bufB_off = alloc((size_t)n * 64 * 4);
    size_t fbuf_off = alloc((size_t)n * 64 * 4);

    float* segs = (float*)(ws + seg_off);
    float* blend = (float*)(ws + blend_off);
    int* cnts = (int*)(ws + cnt_off);
    double* stats = (double*)(ws + stats_off);
    unsigned* gmax = (unsigned*)(ws + gmax_off);
    float* adp = (float*)(ws + adp_off);
    float* bufA = (float*)(ws + bufA_off);
    float* bufB = (float*)(ws + bufB_off);
    float* fbuf = (float*)(ws + fbuf_off);
    float* outp = (float*)d_out;

    hipMemsetAsync(d_ws, 0, zbytes, stream);

    const int MM_BLK = (n + 15) / 16;
    const int CONV_BLK = (n + 63) / 64;
    const int EW_BLK = 2048;
    const int CS_BLK = 1024;

    adp_kernel<<<1024, 256, 0, stream>>>(feat, adaptive_W, adp, n);

    for (int i = 0; i < 3; ++i) {
        const int* clus = clusters + (size_t)i * n;
        int* cnt = cnts + (size_t)i * KCL;
        float* segB = segs + (size_t)(3 * i + 0) * KCL * 64;
        float* seg2 = segs + (size_t)(3 * i + 1) * KCL * 64;
        float* seg3 = segs + (size_t)(3 * i + 2) * KCL * 64;
        double* stA = stats + (size_t)(2 * i + 0) * 128;
        double* stE = stats + (size_t)(2 * i + 1) * 128;

        hist_kernel<<<256, 256, 0, stream>>>(clus, cnt, n);
        // A = feat @ lw_W[i]
        mm64_kernel<0, 0><<<MM_BLK, 256, 0, stream>>>(feat, lw_W + (size_t)i * 4096, bufA, n,
                                                      nullptr, nullptr, nullptr, nullptr);
        colstats_kernel<<<CS_BLK, 256, 0, stream>>>(bufA, n, stA);
        // B = lrelu(bn(A)); segB[c] += B
        bn_lrelu_segsum_kernel<<<EW_BLK, 256, 0, stream>>>(bufA, stA, lw_g + i * 64, lw_b + i * 64,
                                                           bufB, segB, clus, n);
        // C = (B - segB[c]/cnt) @ w_W[i], track global max
        mm64_kernel<2, 1><<<MM_BLK, 256, 0, stream>>>(bufB, w_W + (size_t)i * 4096, bufA, n,
                                                      segB, cnt, clus, gmax + i);
        // D = exp(C - gmax); seg2[c] += D
        exp_segsum_kernel<<<EW_BLK, 256, 0, stream>>>(bufA, gmax + i, seg2, clus, n);
        // E = feat @ proj_W[i]
        mm64_kernel<0, 0><<<MM_BLK, 256, 0, stream>>>(feat, proj_W + (size_t)i * 4096, bufB, n,
                                                      nullptr, nullptr, nullptr, nullptr);
        colstats_kernel<<<CS_BLK, 256, 0, stream>>>(bufB, n, stE);
        // seg3[c] += lrelu(bn(E)) * D/(seg2[c]+1e-6)
        bn_lrelu_mul_segsum_kernel<<<EW_BLK, 256, 0, stream>>>(bufB, stE, proj_g + i * 64, proj_b + i * 64,
                                                               bufA, seg2, seg3, clus, n);
        // blend += adp[:,i] * seg3[c]
        blend_add_kernel<<<EW_BLK, 256, 0, stream>>>(adp, i, seg3, clus, blend, n);
    }

    // P3 = feat @ proj_W[3]
    mm64_kernel<0, 0><<<MM_BLK, 256, 0, stream>>>(feat, proj_W + (size_t)3 * 4096, bufA, n,
                                                  nullptr, nullptr, nullptr, nullptr);
    colstats_kernel<<<CS_BLK, 256, 0, stream>>>(bufA, n, stats + 6 * 128);
    // t3 = [lrelu(bn(P3)), blend] @ fuse_W
    fuse_mm_kernel<<<MM_BLK, 256, 0, stream>>>(bufA, stats + 6 * 128, proj_g + 192, proj_b + 192,
                                               blend, fuse_W, bufB, n);
    colstats_kernel<<<CS_BLK, 256, 0, stream>>>(bufB, n, stats + 7 * 128);
    // f = lrelu(bn(t3)) + feat   (residual)
    bn_lrelu_addfeat_kernel<<<EW_BLK, 256, 0, stream>>>(bufB, stats + 7 * 128, fuse_g, fuse_b, feat, fbuf, n);

    // conv1 -> d_out (scratch), bn1+lrelu in place
    subm_conv_kernel<<<CONV_BLK, 256, 0, stream>>>(fbuf, nbr, conv1_W, outp, n);
    colstats_kernel<<<CS_BLK, 256, 0, stream>>>(outp, n, stats + 8 * 128);
    bn_lrelu_kernel<<<EW_BLK, 256, 0, stream>>>(outp, stats + 8 * 128, bn1_g, bn1_b, n);

    // conv2 -> bufA, then out = lrelu(bn2(conv2) + f)
    subm_conv_kernel<<<CONV_BLK, 256, 0, stream>>>(outp, nbr, conv2_W, bufA, n);
    colstats_kernel<<<CS_BLK, 256, 0, stream>>>(bufA, n, stats + 9 * 128);
    final_kernel<<<EW_BLK, 256, 0, stream>>>(bufA, stats + 9 * 128, bn2_g, bn2_b, fbuf, outp, n);
}

// Round 2
// 1680.584 us; speedup vs baseline: 1.6722x; 1.6722x over previous
//
#include <hip/hip_runtime.h>
#include <hip/hip_bf16.h>
#include <math.h>

#define KCL 2048
#define LRELU_NEG 0.01f
#define EPSBN 1e-5f

using s8v = __attribute__((ext_vector_type(8))) short;   // 8 bf16 (4 VGPRs)
using f4v = __attribute__((ext_vector_type(4))) float;   // MFMA accumulator

__device__ __forceinline__ float lrelu(float x) { return x > 0.f ? x : LRELU_NEG * x; }

// monotonic float->uint encoding for atomicMax over mixed-sign floats
__device__ __forceinline__ unsigned encf(float f) {
    unsigned u = __float_as_uint(f);
    return (u & 0x80000000u) ? ~u : (u | 0x80000000u);
}
__device__ __forceinline__ float decf(unsigned u) {
    return __uint_as_float((u & 0x80000000u) ? (u & 0x7fffffffu) : ~u);
}

// BatchNorm1d training-mode apply from accumulated double sums (stats[0:64]=sum, stats[64:128]=sumsq)
__device__ __forceinline__ float bn_apply(float x, const double* __restrict__ stats, int col, int n,
                                          const float* __restrict__ g, const float* __restrict__ b) {
    float mean = (float)(stats[col] / n);
    float ex2  = (float)(stats[64 + col] / n);
    float var  = ex2 - mean * mean;
    float rstd = rsqrtf(fmaxf(var, 0.f) + EPSBN);
    return (x - mean) * rstd * g[col] + b[col];
}

// ---------------- column stats (sum, sumsq) over (n,64), double atomics ----------------
__global__ __launch_bounds__(256) void colstats_kernel(const float* __restrict__ in, int n,
                                                       double* __restrict__ stats) {
    int t = threadIdx.x;
    int col = t & 63, rg = t >> 6;
    double s = 0.0, s2 = 0.0;
    for (long row = (long)blockIdx.x * 4 + rg; row < n; row += (long)gridDim.x * 4) {
        float x = in[row * 64 + col];
        s += x;
        s2 += (double)x * (double)x;
    }
    __shared__ double red[256];
    red[t] = s;
    __syncthreads();
    if (t < 64) atomicAdd(&stats[col], red[t] + red[t + 64] + red[t + 128] + red[t + 192]);
    __syncthreads();
    red[t] = s2;
    __syncthreads();
    if (t < 64) atomicAdd(&stats[64 + col], red[t] + red[t + 64] + red[t + 128] + red[t + 192]);
}

// ---------------- cluster histogram ----------------
__global__ __launch_bounds__(256) void hist_kernel(const int* __restrict__ clus, int* __restrict__ cnt, int n) {
    __shared__ int h[KCL];
    for (int i = threadIdx.x; i < KCL; i += 256) h[i] = 0;
    __syncthreads();
    for (long i = (long)blockIdx.x * 256 + threadIdx.x; i < n; i += (long)gridDim.x * 256)
        atomicAdd(&h[clus[i]], 1);
    __syncthreads();
    for (int i = threadIdx.x; i < KCL; i += 256) {
        int v = h[i];
        if (v) atomicAdd(&cnt[i], v);
    }
}

// ---------------- adaptive weights: softmax(feat @ aW[64,3], axis=1) ----------------
__global__ __launch_bounds__(256) void adp_kernel(const float* __restrict__ feat, const float* __restrict__ aW,
                                                  float* __restrict__ adp, int n) {
    __shared__ float w[192];
    for (int i = threadIdx.x; i < 192; i += 256) w[i] = aW[i];
    __syncthreads();
    for (long row = (long)blockIdx.x * 256 + threadIdx.x; row < n; row += (long)gridDim.x * 256) {
        const float* fr = feat + row * 64;
        float l0 = 0.f, l1 = 0.f, l2 = 0.f;
#pragma unroll 8
        for (int k = 0; k < 64; ++k) {
            float x = fr[k];
            l0 += x * w[k * 3 + 0];
            l1 += x * w[k * 3 + 1];
            l2 += x * w[k * 3 + 2];
        }
        float m = fmaxf(l0, fmaxf(l1, l2));
        float e0 = expf(l0 - m), e1 = expf(l1 - m), e2 = expf(l2 - m);
        float inv = 1.f / (e0 + e1 + e2);
        adp[row * 3 + 0] = e0 * inv;
        adp[row * 3 + 1] = e1 * inv;
        adp[row * 3 + 2] = e2 * inv;
    }
}

// ---------------- (n,64) @ (64,64) with optional pre/post ops ----------------
template <int PRE, int PMAX>
__global__ __launch_bounds__(256) void mm64_kernel(const float* __restrict__ in, const float* __restrict__ W,
                                                   float* __restrict__ out, int n,
                                                   const float* __restrict__ seg, const int* __restrict__ cnt,
                                                   const int* __restrict__ clus, unsigned* __restrict__ gmaxp) {
    __shared__ float Wl[64 * 64];
    __shared__ float rs[16 * 64];
    int t = threadIdx.x;
    int col = t & 63, r0 = t >> 6;
    for (int i = t; i < 4096; i += 256) Wl[i] = W[i];
    int rb = blockIdx.x * 16;
    for (int rr = r0; rr < 16; rr += 4) {
        int row = rb + rr;
        float x = 0.f;
        if (row < n) {
            x = in[(size_t)row * 64 + col];
            if (PRE == 2) {
                int c = clus[row];
                float cf = (float)cnt[c];
                if (cf < 1.f) cf = 1.f;
                x -= seg[c * 64 + col] / cf;
            }
        }
        rs[rr * 64 + col] = x;
    }
    __syncthreads();
    float a0 = 0.f, a1 = 0.f, a2 = 0.f, a3 = 0.f;
#pragma unroll 8
    for (int kk = 0; kk < 64; ++kk) {
        float wv = Wl[kk * 64 + col];
        a0 += rs[(r0 + 0) * 64 + kk] * wv;
        a1 += rs[(r0 + 4) * 64 + kk] * wv;
        a2 += rs[(r0 + 8) * 64 + kk] * wv;
        a3 += rs[(r0 + 12) * 64 + kk] * wv;
    }
    if (rb + r0 + 0 < n) out[(size_t)(rb + r0 + 0) * 64 + col] = a0;
    if (rb + r0 + 4 < n) out[(size_t)(rb + r0 + 4) * 64 + col] = a1;
    if (rb + r0 + 8 < n) out[(size_t)(rb + r0 + 8) * 64 + col] = a2;
    if (rb + r0 + 12 < n) out[(size_t)(rb + r0 + 12) * 64 + col] = a3;
    if constexpr (PMAX) {
        float m = -INFINITY;
        if (rb + r0 + 0 < n) m = fmaxf(m, a0);
        if (rb + r0 + 4 < n) m = fmaxf(m, a1);
        if (rb + r0 + 8 < n) m = fmaxf(m, a2);
        if (rb + r0 + 12 < n) m = fmaxf(m, a3);
        __shared__ float red[256];
        red[t] = m;
        __syncthreads();
        for (int s = 128; s > 0; s >>= 1) {
            if (t < s) red[t] = fmaxf(red[t], red[t + s]);
            __syncthreads();
        }
        if (t == 0) atomicMax(gmaxp, encf(red[0]));
    }
}

// ---------------- B = lrelu(bn(A)); seg[c] += B ----------------
__global__ __launch_bounds__(256) void bn_lrelu_segsum_kernel(const float* __restrict__ A,
                                                              const double* __restrict__ stats,
                                                              const float* __restrict__ g, const float* __restrict__ b,
                                                              float* __restrict__ B, float* __restrict__ seg,
                                                              const int* __restrict__ clus, int n) {
    long total = (long)n * 64;
    for (long idx = (long)blockIdx.x * 256 + threadIdx.x; idx < total; idx += (long)gridDim.x * 256) {
        int col = (int)(idx & 63);
        long row = idx >> 6;
        float y = lrelu(bn_apply(A[idx], stats, col, n, g, b));
        B[idx] = y;
        atomicAdd(&seg[(long)clus[row] * 64 + col], y);
    }
}

// ---------------- D = exp(C - gmax) in-place; seg2[c] += D ----------------
__global__ __launch_bounds__(256) void exp_segsum_kernel(float* __restrict__ C, const unsigned* __restrict__ gmaxp,
                                                         float* __restrict__ seg2, const int* __restrict__ clus, int n) {
    float gm = decf(*gmaxp);
    long total = (long)n * 64;
    for (long idx = (long)blockIdx.x * 256 + threadIdx.x; idx < total; idx += (long)gridDim.x * 256) {
        int col = (int)(idx & 63);
        long row = idx >> 6;
        float y = expf(C[idx] - gm);
        C[idx] = y;
        atomicAdd(&seg2[(long)clus[row] * 64 + col], y);
    }
}

// ---------------- pf = lrelu(bn(E)); seg3[c] += pf * D/(seg2[c]+1e-6) ----------------
__global__ __launch_bounds__(256) void bn_lrelu_mul_segsum_kernel(const float* __restrict__ E,
                                                                  const double* __restrict__ stats,
                                                                  const float* __restrict__ g,
                                                                  const float* __restrict__ b,
                                                                  const float* __restrict__ D,
                                                                  const float* __restrict__ seg2,
                                                                  float* __restrict__ seg3,
                                                                  const int* __restrict__ clus, int n) {
    long total = (long)n * 64;
    for (long idx = (long)blockIdx.x * 256 + threadIdx.x; idx < total; idx += (long)gridDim.x * 256) {
        int col = (int)(idx & 63);
        long row = idx >> 6;
        int c = clus[row];
        float pf = lrelu(bn_apply(E[idx], stats, col, n, g, b));
        float pw = D[idx] / (seg2[(long)c * 64 + col] + 1e-6f);
        atomicAdd(&seg3[(long)c * 64 + col], pf * pw);
    }
}

// ---------------- blend += adp[:,lvl] * seg3[c] ----------------
__global__ __launch_bounds__(256) void blend_add_kernel(const float* __restrict__ adp, int lvl,
                                                        const float* __restrict__ seg3, const int* __restrict__ clus,
                                                        float* __restrict__ blend, int n) {
    long total = (long)n * 64;
    for (long idx = (long)blockIdx.x * 256 + threadIdx.x; idx < total; idx += (long)gridDim.x * 256) {
        int col = (int)(idx & 63);
        long row = idx >> 6;
        blend[idx] += adp[row * 3 + lvl] * seg3[(long)clus[row] * 64 + col];
    }
}

// ---------------- t3 = lrelu(bn(P3)) @ Wf[0:64] + blend @ Wf[64:128] ----------------
__global__ __launch_bounds__(256) void fuse_mm_kernel(const float* __restrict__ P3, const double* __restrict__ stats,
                                                      const float* __restrict__ g, const float* __restrict__ b,
                                                      const float* __restrict__ blend, const float* __restrict__ Wf,
                                                      float* __restrict__ out, int n) {
    __shared__ float Wl[128 * 64];
    __shared__ float rs[16 * 128];
    int t = threadIdx.x;
    int col = t & 63, r0 = t >> 6;
    for (int i = t; i < 128 * 64; i += 256) Wl[i] = Wf[i];
    int rb = blockIdx.x * 16;
    for (int rr = r0; rr < 16; rr += 4) {
        int row = rb + rr;
        float xa = 0.f, xb = 0.f;
        if (row < n) {
            xa = lrelu(bn_apply(P3[(size_t)row * 64 + col], stats, col, n, g, b));
            xb = blend[(size_t)row * 64 + col];
        }
        rs[rr * 128 + col] = xa;
        rs[rr * 128 + 64 + col] = xb;
    }
    __syncthreads();
    float a0 = 0.f, a1 = 0.f, a2 = 0.f, a3 = 0.f;
#pragma unroll 8
    for (int kk = 0; kk < 128; ++kk) {
        float wv = Wl[kk * 64 + col];
        a0 += rs[(r0 + 0) * 128 + kk] * wv;
        a1 += rs[(r0 + 4) * 128 + kk] * wv;
        a2 += rs[(r0 + 8) * 128 + kk] * wv;
        a3 += rs[(r0 + 12) * 128 + kk] * wv;
    }
    if (rb + r0 + 0 < n) out[(size_t)(rb + r0 + 0) * 64 + col] = a0;
    if (rb + r0 + 4 < n) out[(size_t)(rb + r0 + 4) * 64 + col] = a1;
    if (rb + r0 + 8 < n) out[(size_t)(rb + r0 + 8) * 64 + col] = a2;
    if (rb + r0 + 12 < n) out[(size_t)(rb + r0 + 12) * 64 + col] = a3;
}

// ---------------- f = lrelu(bn(t3)) + feat  -> bf16 ----------------
__global__ __launch_bounds__(256) void bn_lrelu_addfeat_kernel(const float* __restrict__ t3,
                                                               const double* __restrict__ stats,
                                                               const float* __restrict__ g, const float* __restrict__ b,
                                                               const float* __restrict__ feat,
                                                               __hip_bfloat16* __restrict__ f16, int n) {
    long total = (long)n * 64;
    for (long idx = (long)blockIdx.x * 256 + threadIdx.x; idx < total; idx += (long)gridDim.x * 256) {
        int col = (int)(idx & 63);
        f16[idx] = __float2bfloat16(lrelu(bn_apply(t3[idx], stats, col, n, g, b)) + feat[idx]);
    }
}

// ---------------- o16 = bf16(lrelu(bn(v))) ----------------
__global__ __launch_bounds__(256) void bn_lrelu_tobf16_kernel(const float* __restrict__ v,
                                                              const double* __restrict__ stats,
                                                              const float* __restrict__ g, const float* __restrict__ b,
                                                              __hip_bfloat16* __restrict__ o16, int n) {
    long total = (long)n * 64;
    for (long idx = (long)blockIdx.x * 256 + threadIdx.x; idx < total; idx += (long)gridDim.x * 256) {
        int col = (int)(idx & 63);
        o16[idx] = __float2bfloat16(lrelu(bn_apply(v[idx], stats, col, n, g, b)));
    }
}

// ---------------- out = lrelu(bn(w) + f16) ----------------
__global__ __launch_bounds__(256) void final_kernel(const float* __restrict__ w, const double* __restrict__ stats,
                                                    const float* __restrict__ g, const float* __restrict__ b,
                                                    const __hip_bfloat16* __restrict__ f16, float* __restrict__ out,
                                                    int n) {
    long total = (long)n * 64;
    for (long idx = (long)blockIdx.x * 256 + threadIdx.x; idx < total; idx += (long)gridDim.x * 256) {
        int col = (int)(idx & 63);
        out[idx] = lrelu(bn_apply(w[idx], stats, col, n, g, b) + __bfloat162float(f16[idx]));
    }
}

// ---------------- weight prep: Wt[b][col][k] = bf16(W[b][k][col]) for 54 matrices ----------------
__global__ __launch_bounds__(256) void prep_wt_kernel(const float* __restrict__ W1, const float* __restrict__ W2,
                                                      __hip_bfloat16* __restrict__ Wt) {
    int bk = blockIdx.x;  // 0..53
    const float* W = (bk < 27) ? (W1 + (size_t)bk * 4096) : (W2 + (size_t)(bk - 27) * 4096);
    __hip_bfloat16* o = Wt + (size_t)bk * 4096;
    for (int i = threadIdx.x; i < 4096; i += 256) {
        int kk = i >> 6, cc = i & 63;
        o[cc * 64 + kk] = __float2bfloat16(W[i]);
    }
}

// ---------------- submanifold conv, bf16 MFMA 16x16x32, 128x64 tile ----------------
// LDS tiles XOR-swizzled at 16B-chunk granularity: chunk c of row r stored at slot c^(r&7).
// A/B fragments loaded with identical contiguous-8-K convention (layout-symmetric => safe).
__global__ __launch_bounds__(256) void subm_conv_mfma_kernel(const __hip_bfloat16* __restrict__ fin,
                                                             const int* __restrict__ nbr,
                                                             const __hip_bfloat16* __restrict__ Wt,
                                                             float* __restrict__ vout, int n) {
    __shared__ uint4 As[128 * 8];  // 128 rows x 64 bf16 (8 chunks of 16B), swizzled
    __shared__ uint4 Ws[64 * 8];   // 64 cols  x 64 bf16, swizzled
    int t = threadIdx.x;
    int lane = t & 63, w = t >> 6;
    int rb = blockIdx.x * 128;
    int arow = t >> 1, ah = t & 1;   // A staging: 2 threads/row, 4 chunks each
    int wrow = t >> 2, wq = t & 3;   // W staging: 4 threads/row, 2 chunks each
    const int l15 = lane & 15, lg = lane >> 4;
    int rowA0 = w * 32 + l15, rowA1 = rowA0 + 16;
    int swA0 = rowA0 & 7, swA1 = rowA1 & 7;

    f4v acc[2][4];
#pragma unroll
    for (int rf = 0; rf < 2; ++rf)
#pragma unroll
        for (int nf = 0; nf < 4; ++nf)
#pragma unroll
            for (int j = 0; j < 4; ++j) acc[rf][nf][j] = 0.f;

    for (int k = 0; k < 27; ++k) {
        __syncthreads();
        // stage A (gathered rows)
        int gi = (rb + arow < n) ? nbr[(size_t)k * n + rb + arow] : -1;
        uint4 v0 = {0, 0, 0, 0}, v1 = {0, 0, 0, 0}, v2 = {0, 0, 0, 0}, v3 = {0, 0, 0, 0};
        if (gi >= 0) {
            const uint4* src = (const uint4*)(fin + (size_t)gi * 64) + ah * 4;
            v0 = src[0]; v1 = src[1]; v2 = src[2]; v3 = src[3];
        }
        {
            int sw = arow & 7;
            uint4* dst = As + arow * 8;
            dst[(ah * 4 + 0) ^ sw] = v0;
            dst[(ah * 4 + 1) ^ sw] = v1;
            dst[(ah * 4 + 2) ^ sw] = v2;
            dst[(ah * 4 + 3) ^ sw] = v3;
        }
        // stage W (already transposed: row = out col, contiguous K)
        {
            const uint4* src = (const uint4*)(Wt + (size_t)k * 4096 + wrow * 64);
            int sw = wrow & 7;
            uint4* dst = Ws + wrow * 8;
            dst[wq ^ sw] = src[wq];
            dst[(wq + 4) ^ sw] = src[wq + 4];
        }
        __syncthreads();
        const s8v* Av = (const s8v*)As;
        const s8v* Wv = (const s8v*)Ws;
#pragma unroll
        for (int kb = 0; kb < 2; ++kb) {
            int g = kb * 4 + lg;
            s8v a0 = Av[rowA0 * 8 + (g ^ swA0)];
            s8v a1 = Av[rowA1 * 8 + (g ^ swA1)];
#pragma unroll
            for (int nf = 0; nf < 4; ++nf) {
                int col = nf * 16 + l15;
                s8v bf = Wv[col * 8 + (g ^ (col & 7))];
                acc[0][nf] = __builtin_amdgcn_mfma_f32_16x16x32_bf16(a0, bf, acc[0][nf], 0, 0, 0);
                acc[1][nf] = __builtin_amdgcn_mfma_f32_16x16x32_bf16(a1, bf, acc[1][nf], 0, 0, 0);
            }
        }
    }
    // C/D layout: col = lane&15, row = (lane>>4)*4 + reg  [m89-verified]
    int base = rb + w * 32;
#pragma unroll
    for (int rf = 0; rf < 2; ++rf)
#pragma unroll
        for (int nf = 0; nf < 4; ++nf)
#pragma unroll
            for (int j = 0; j < 4; ++j) {
                int row = base + rf * 16 + lg * 4 + j;
                if (row < n) vout[(size_t)row * 64 + nf * 16 + l15] = acc[rf][nf][j];
            }
}

extern "C" void kernel_launch(void* const* d_in, const int* in_sizes, int n_in,
                              void* d_out, int out_size, void* d_ws, size_t ws_size,
                              hipStream_t stream) {
    const float* feat = (const float*)d_in[0];
    const float* lw_W = (const float*)d_in[1];
    const float* lw_g = (const float*)d_in[2];
    const float* lw_b = (const float*)d_in[3];
    const float* w_W = (const float*)d_in[4];
    const float* proj_W = (const float*)d_in[5];
    const float* proj_g = (const float*)d_in[6];
    const float* proj_b = (const float*)d_in[7];
    const float* adaptive_W = (const float*)d_in[8];
    const float* fuse_W = (const float*)d_in[9];
    const float* fuse_g = (const float*)d_in[10];
    const float* fuse_b = (const float*)d_in[11];
    const float* conv1_W = (const float*)d_in[12];
    const float* bn1_g = (const float*)d_in[13];
    const float* bn1_b = (const float*)d_in[14];
    const float* conv2_W = (const float*)d_in[15];
    const float* bn2_g = (const float*)d_in[16];
    const float* bn2_b = (const float*)d_in[17];
    const int* clusters = (const int*)d_in[18];
    const int* nbr = (const int*)d_in[19];

    const int n = in_sizes[0] / 64;

    char* ws = (char*)d_ws;
    size_t off = 0;
    auto alloc = [&](size_t bytes) -> size_t {
        size_t o = off;
        off = (off + bytes + 255) & ~(size_t)255;
        return o;
    };
    size_t seg_off = alloc((size_t)9 * KCL * 64 * 4);
    size_t blend_off = alloc((size_t)n * 64 * 4);
    size_t cnt_off = alloc((size_t)3 * KCL * 4);
    size_t stats_off = alloc((size_t)10 * 128 * 8);
    size_t gmax_off = alloc(16);
    size_t zbytes = off;  // zeroed region ends here
    size_t adp_off = alloc((size_t)n * 3 * 4);
    size_t bufA_off = alloc((size_t)n * 64 * 4);
    size_t bufB_off = alloc((size_t)n * 64 * 4);
    size_t fbuf16_off = alloc((size_t)n * 64 * 2);
    size_t cbuf16_off = alloc((size_t)n * 64 * 2);
    size_t wt_off = alloc((size_t)54 * 4096 * 2);

    float* segs = (float*)(ws + seg_off);
    float* blend = (float*)(ws + blend_off);
    int* cnts = (int*)(ws + cnt_off);
    double* stats = (double*)(ws + stats_off);
    unsigned* gmax = (unsigned*)(ws + gmax_off);
    float* adp = (float*)(ws + adp_off);
    float* bufA = (float*)(ws + bufA_off);
    float* bufB = (float*)(ws + bufB_off);
    __hip_bfloat16* fbuf16 = (__hip_bfloat16*)(ws + fbuf16_off);
    __hip_bfloat16* cbuf16 = (__hip_bfloat16*)(ws + cbuf16_off);
    __hip_bfloat16* wt = (__hip_bfloat16*)(ws + wt_off);
    float* outp = (float*)d_out;

    hipMemsetAsync(d_ws, 0, zbytes, stream);

    const int MM_BLK = (n + 15) / 16;
    const int CONV_BLK = (n + 127) / 128;
    const int EW_BLK = 2048;
    const int CS_BLK = 1024;

    prep_wt_kernel<<<54, 256, 0, stream>>>(conv1_W, conv2_W, wt);
    adp_kernel<<<1024, 256, 0, stream>>>(feat, adaptive_W, adp, n);

    for (int i = 0; i < 3; ++i) {
        const int* clus = clusters + (size_t)i * n;
        int* cnt = cnts + (size_t)i * KCL;
        float* segB = segs + (size_t)(3 * i + 0) * KCL * 64;
        float* seg2 = segs + (size_t)(3 * i + 1) * KCL * 64;
        float* seg3 = segs + (size_t)(3 * i + 2) * KCL * 64;
        double* stA = stats + (size_t)(2 * i + 0) * 128;
        double* stE = stats + (size_t)(2 * i + 1) * 128;

        hist_kernel<<<256, 256, 0, stream>>>(clus, cnt, n);
        mm64_kernel<0, 0><<<MM_BLK, 256, 0, stream>>>(feat, lw_W + (size_t)i * 4096, bufA, n,
                                                      nullptr, nullptr, nullptr, nullptr);
        colstats_kernel<<<CS_BLK, 256, 0, stream>>>(bufA, n, stA);
        bn_lrelu_segsum_kernel<<<EW_BLK, 256, 0, stream>>>(bufA, stA, lw_g + i * 64, lw_b + i * 64,
                                                           bufB, segB, clus, n);
        mm64_kernel<2, 1><<<MM_BLK, 256, 0, stream>>>(bufB, w_W + (size_t)i * 4096, bufA, n,
                                                      segB, cnt, clus, gmax + i);
        exp_segsum_kernel<<<EW_BLK, 256, 0, stream>>>(bufA, gmax + i, seg2, clus, n);
        mm64_kernel<0, 0><<<MM_BLK, 256, 0, stream>>>(feat, proj_W + (size_t)i * 4096, bufB, n,
                                                      nullptr, nullptr, nullptr, nullptr);
        colstats_kernel<<<CS_BLK, 256, 0, stream>>>(bufB, n, stE);
        bn_lrelu_mul_segsum_kernel<<<EW_BLK, 256, 0, stream>>>(bufB, stE, proj_g + i * 64, proj_b + i * 64,
                                                               bufA, seg2, seg3, clus, n);
        blend_add_kernel<<<EW_BLK, 256, 0, stream>>>(adp, i, seg3, clus, blend, n);
    }

    // P3 = feat @ proj_W[3]
    mm64_kernel<0, 0><<<MM_BLK, 256, 0, stream>>>(feat, proj_W + (size_t)3 * 4096, bufA, n,
                                                  nullptr, nullptr, nullptr, nullptr);
    colstats_kernel<<<CS_BLK, 256, 0, stream>>>(bufA, n, stats + 6 * 128);
    fuse_mm_kernel<<<MM_BLK, 256, 0, stream>>>(bufA, stats + 6 * 128, proj_g + 192, proj_b + 192,
                                               blend, fuse_W, bufB, n);
    colstats_kernel<<<CS_BLK, 256, 0, stream>>>(bufB, n, stats + 7 * 128);
    // f = lrelu(bn(t3)) + feat  (bf16)
    bn_lrelu_addfeat_kernel<<<EW_BLK, 256, 0, stream>>>(bufB, stats + 7 * 128, fuse_g, fuse_b, feat,
                                                        fbuf16, n);

    // conv1 (bf16 MFMA) -> d_out scratch (fp32), then bn1+lrelu -> bf16
    subm_conv_mfma_kernel<<<CONV_BLK, 256, 0, stream>>>(fbuf16, nbr, wt, outp, n);
    colstats_kernel<<<CS_BLK, 256, 0, stream>>>(outp, n, stats + 8 * 128);
    bn_lrelu_tobf16_kernel<<<EW_BLK, 256, 0, stream>>>(outp, stats + 8 * 128, bn1_g, bn1_b, cbuf16, n);

    // conv2 (bf16 MFMA) -> bufA, then out = lrelu(bn2(conv2) + f)
    subm_conv_mfma_kernel<<<CONV_BLK, 256, 0, stream>>>(cbuf16, nbr, wt + (size_t)27 * 4096, bufA, n);
    colstats_kernel<<<CS_BLK, 256, 0, stream>>>(bufA, n, stats + 9 * 128);
    final_kernel<<<EW_BLK, 256, 0, stream>>>(bufA, stats + 9 * 128, bn2_g, bn2_b, fbuf16, outp, n);
}